// Round 3
// baseline (651.682 us; speedup 1.0000x reference)
//
#include <hip/hip_runtime.h>

// LateralInhibitionLIFCell: one block per row, winner-take-all lateral inhibition.
// Traffic: 3 fp32 reads + 3 fp32 writes of [4096, 8192] = ~805 MB -> memory-bound,
// ~128 us floor at 6.3 TB/s.
//
// R1: removed float4 vn[8] register array; no-spike fallback re-reads inputs.
// __launch_bounds__(256,8) pins 8 waves/SIMD; nontemporal streaming stores.
// R2: __builtin_nontemporal_store needs a NATIVE vector type, not HIP's
// float4 class -> use ext_vector_type(4) float throughout.

constexpr int B = 4096;
constexpr int N = 8192;
constexpr int BLOCK = 256;
constexpr int CHUNKS = N / (BLOCK * 4);  // 8 float4 chunks per thread

typedef float fx4 __attribute__((ext_vector_type(4)));

#define NEG_FLT_MAX (-3.402823466e38f)

__device__ __forceinline__ void combine_argmax(float& bv, int& bi, float ov, int oi) {
    // first-max semantics: strictly greater wins; on tie, smaller index wins
    if (ov > bv || (ov == bv && oi < bi)) { bv = ov; bi = oi; }
}

// Exact per-op rounding (__*_rn) to match numpy fp32 bit-for-bit: z is binary and
// the argmax winner swings v_out by 5.0, so ulp drift from FMA contraction can
// blow past the absmax threshold.
__device__ __forceinline__ float lif_inew(float x, float i) {
    return __fadd_rn(i, __fmul_rn(0.5f, __fsub_rn(x, i)));
}
__device__ __forceinline__ float lif_vnew(float v, float inew) {
    return __fadd_rn(v, __fmul_rn(0.5f, __fsub_rn(inew, v)));
}

__global__ __launch_bounds__(BLOCK, 8) void lif_wta_kernel(
    const float* __restrict__ x_in,
    const float* __restrict__ v_in,
    const float* __restrict__ i_in,
    float* __restrict__ z_out,
    float* __restrict__ v_out,
    float* __restrict__ i_out)
{
    const int row = blockIdx.x;
    const int tid = threadIdx.x;
    const size_t base = (size_t)row * N;

    const fx4* x4 = reinterpret_cast<const fx4*>(x_in + base);
    const fx4* v4 = reinterpret_cast<const fx4*>(v_in + base);
    const fx4* c4 = reinterpret_cast<const fx4*>(i_in + base);
    fx4* z4 = reinterpret_cast<fx4*>(z_out + base);
    fx4* o4 = reinterpret_cast<fx4*>(v_out + base);
    fx4* i4 = reinterpret_cast<fx4*>(i_out + base);

    float best_val = NEG_FLT_MAX;
    int   best_idx = 0x7fffffff;

#pragma unroll 2
    for (int k = 0; k < CHUNKS; ++k) {
        const int c = tid + k * BLOCK;   // float4 chunk index (coalesced)
        const fx4 xx = x4[c];
        const fx4 vv = v4[c];
        const fx4 ii = c4[c];
        fx4 in4, zz;
        const int e0 = c * 4;

#pragma unroll
        for (int j = 0; j < 4; ++j) {
            float inew = lif_inew(xx[j], ii[j]);
            float vnew = lif_vnew(vv[j], inew);
            in4[j] = inew;
            zz[j] = (vnew >= 1.0f) ? 1.0f : 0.0f;
            // ascending-index scan: strict > keeps first max
            if (vnew >= 1.0f && vnew > best_val) {
                best_val = vnew; best_idx = e0 + j;
            }
        }

        __builtin_nontemporal_store(zz, &z4[c]);
        __builtin_nontemporal_store(in4, &i4[c]);
    }

    // --- block-wide argmax reduction (64-lane wave shuffle, then LDS) ---
#pragma unroll
    for (int off = 32; off > 0; off >>= 1) {
        float ov = __shfl_down(best_val, off);
        int   oi = __shfl_down(best_idx, off);
        combine_argmax(best_val, best_idx, ov, oi);
    }

    __shared__ float s_val[BLOCK / 64];
    __shared__ int   s_idx[BLOCK / 64];
    __shared__ float s_bval;
    __shared__ int   s_bidx;

    const int wave = tid >> 6;
    const int lane = tid & 63;
    if (lane == 0) { s_val[wave] = best_val; s_idx[wave] = best_idx; }
    __syncthreads();
    if (tid == 0) {
        float bv = s_val[0]; int bi = s_idx[0];
#pragma unroll
        for (int w = 1; w < BLOCK / 64; ++w) combine_argmax(bv, bi, s_val[w], s_idx[w]);
        s_bval = bv; s_bidx = bi;
    }
    __syncthreads();
    const float row_best = s_bval;
    const int   winner   = s_bidx;

    // --- v_out write ---
    if (row_best >= 1.0f) {
        // Row has >=1 spike: winner gets V_RESET (it spiked), everyone else -5.
        // No dependence on v_new. This is the ~always path.
#pragma unroll 2
        for (int k = 0; k < CHUNKS; ++k) {
            const int c = tid + k * BLOCK;
            const int e0 = c * 4;
            fx4 o;
#pragma unroll
            for (int j = 0; j < 4; ++j)
                o[j] = (e0 + j == winner) ? 0.0f : -5.0f;
            __builtin_nontemporal_store(o, &o4[c]);
        }
    } else {
        // No spikes anywhere in the row (P ~ e^-155 here): v_out = v_new.
        // Re-read inputs (row data is L1/L2-warm) and recompute.
#pragma unroll 2
        for (int k = 0; k < CHUNKS; ++k) {
            const int c = tid + k * BLOCK;
            const fx4 xx = x4[c];
            const fx4 vv = v4[c];
            const fx4 ii = c4[c];
            fx4 o;
#pragma unroll
            for (int j = 0; j < 4; ++j)
                o[j] = lif_vnew(vv[j], lif_inew(xx[j], ii[j]));
            __builtin_nontemporal_store(o, &o4[c]);
        }
    }
}

extern "C" void kernel_launch(void* const* d_in, const int* in_sizes, int n_in,
                              void* d_out, int out_size, void* d_ws, size_t ws_size,
                              hipStream_t stream) {
    const float* x = (const float*)d_in[0];
    const float* v = (const float*)d_in[1];
    const float* i = (const float*)d_in[2];

    float* out   = (float*)d_out;
    float* z_out = out;
    float* v_out = out + (size_t)B * N;
    float* i_out = out + 2 * (size_t)B * N;

    lif_wta_kernel<<<B, BLOCK, 0, stream>>>(x, v, i, z_out, v_out, i_out);
}